// Round 13
// baseline (775.477 us; speedup 1.0000x reference)
//
#include <hip/hip_runtime.h>
#include <math.h>

// FermiNet-like forward, N=1024, DIM=3, all fp32.
//
// v13 (from v12/v10 = 415us total; k2 229us):
//  * k2 DS-pipe cut: pipe accounting says k2 is co-bound VALU(~80us) +
//    DS(~100-128us/CU), and the dominant DS term is the 384 per-wave sPQ
//    broadcast reads -- each tile re-reads tile-INVARIANT P/Q. v13 batches
//    4 tiles/pass (2 passes): P/Q read once per (t,sub) and held in regs
//    across 4 tiles -> sPQ reads 384->96, total DS ~800->~480 per wave.
//    Trig loads gain 4-tile ILP. Live ~110 floats fits the (512,4) 128-VGPR
//    cap (v9/v10-proven regime, no spill).
//  * Matvec/barrier/exchange structure byte-identical; all m-loops fully
//    unrolled (constant indices -> registers, no scratch).
//  * k1, h1_all identical to v12. Tail (~185us) is harness-fixed.

#define NP 1024

// ---- workspace offsets (in floats) ----
static const size_t OF_TROW = 0;                    // NP*56 row-major trig
static const size_t OF_CSUM = OF_TROW + NP*56;      // 24  sum_i cos
static const size_t OF_SSUM = OF_CSUM + 24;         // 24  sum_i sin
static const size_t OF_HSUM = OF_SSUM + 24;         // 3*64  h1 row-sum per layer
static const size_t OF_CNT  = OF_HSUM + 192;        // 4 (int counter in [0])
static const size_t OF_RACC = OF_CNT + 4;           // 1024  sum_i r(i,j)
static const size_t OF_M0   = OF_RACC + NP;         // 1024*32 sum_i h2 stage0
static const size_t OF_M1   = OF_M0 + NP*32;        // 1024*32 stage1
static const size_t OF_M2   = OF_M1 + NP*32;        // 1024*32 stage2
// end: OF_M2 + NP*32 = 156388 floats (~626 KB)

__device__ __forceinline__ float ftanh(float x) {
    float e = __expf(2.0f * x);
    return 1.0f - __fdividef(2.0f, e + 1.0f);
}

// ---------------------------------------------------------------------------
// K1: per-particle trig rows (TROW[i][56]) + column sums + zero HSUM/CNT.
// ---------------------------------------------------------------------------
__global__ __launch_bounds__(1024) void k1_tables(
    const float* __restrict__ X,
    float* __restrict__ TROW,
    float* __restrict__ CSUM, float* __restrict__ SSUM,
    float* __restrict__ HSUM, int* __restrict__ CNT)
{
    const int i = threadIdx.x;
    float ck[24], sk[24], cp[3], sp[3];
#pragma unroll
    for (int d = 0; d < 3; ++d) {
        float x = X[i*3 + d];
        sincospif(x, &sp[d], &cp[d]);
#pragma unroll
        for (int k = 0; k < 8; ++k) {
            float s, c;
            sincospif(2.0f*(float)(k+1)*x, &s, &c);
            ck[k*3 + d] = c;  sk[k*3 + d] = s;
        }
    }
    float4* row = (float4*)(TROW + (size_t)i*56);
#pragma unroll
    for (int t = 0; t < 12; ++t)
        row[t] = make_float4(ck[2*t], sk[2*t], ck[2*t+1], sk[2*t+1]);
    row[12] = make_float4(cp[0], sp[0], cp[1], sp[1]);
    row[13] = make_float4(cp[2], sp[2], 0.f, 0.f);

    __shared__ float part[48*16];
    const int lane = i & 63, wv = i >> 6;
#pragma unroll
    for (int v = 0; v < 24; ++v) {
        float a = ck[v], b = sk[v];
#pragma unroll
        for (int off = 32; off; off >>= 1) {
            a += __shfl_down(a, off, 64);
            b += __shfl_down(b, off, 64);
        }
        if (lane == 0) { part[v*16 + wv] = a; part[(24+v)*16 + wv] = b; }
    }
    __syncthreads();
    if (i < 48) {
        float s = 0.f;
#pragma unroll
        for (int w = 0; w < 16; ++w) s += part[i*16 + w];
        if (i < 24) CSUM[i] = s; else SSUM[i-24] = s;
    }
    if (i < 192) HSUM[i] = 0.0f;
    if (i == 200) CNT[0] = 0;
}

// ---------------------------------------------------------------------------
// K2: pair kernel. Block = column j, 512 threads = 8 waves.
// v13: 4-tile batched feature phase (P/Q regs reused across tiles);
// per-tile matvec phases unchanged from v10.
// ---------------------------------------------------------------------------
__global__ __launch_bounds__(512, 4) void k2_pairs(
    const float* __restrict__ W20, const float* __restrict__ b20,
    const float* __restrict__ W21, const float* __restrict__ b21,
    const float* __restrict__ W22, const float* __restrict__ b22,
    const float* __restrict__ TROW,
    float* __restrict__ RACC, float* __restrict__ M0,
    float* __restrict__ M1, float* __restrict__ M2)
{
    __shared__ __align__(16) float sH0[128*32];   // 16 KB, XOR-swizzled slots
    __shared__ __align__(16) float sH1[128*32];   // 16 KB
    __shared__ __align__(16) float sJ[56];        // row j of TROW
    __shared__ __align__(16) float sPQ[24*64];    // [kd][0:32]=P, [32:64]=Q

    const int tid  = threadIdx.x;
    const int lane = tid & 63;
    const int wid  = __builtin_amdgcn_readfirstlane(tid >> 6);   // 0..7 uniform
    const int c0   = wid * 4;                                    // uniform
    const int j    = blockIdx.x;
    const int lx   = lane & 7;

    if (tid < 14) ((float4*)sJ)[tid] = ((const float4*)(TROW + (size_t)j*56))[tid];

    // biases: wave-uniform -> SGPRs
    const float b0x = b20[c0+0], b0y = b20[c0+1], b0z = b20[c0+2], b0w = b20[c0+3];
    const float b1x = b21[c0+0], b1y = b21[c0+1], b1z = b21[c0+2], b1w = b21[c0+3];
    const float b2x = b22[c0+0], b2y = b22[c0+1], b2z = b22[c0+2], b2w = b22[c0+3];
    __syncthreads();

    // ---- fold P/Q for this column j (once per block) ----
    for (int idx = tid; idx < 24*64; idx += 512) {
        const int kd = idx >> 6;
        const int e  = idx & 63;
        const int c  = e & 31;
        const int k = kd/3, d = kd - k*3;
        const float wcv = W20[(1 + k*6 + d)*32 + c];
        const float wsv = W20[(4 + k*6 + d)*32 + c];
        const float cj = sJ[2*kd], sj = sJ[2*kd+1];
        sPQ[idx] = (e < 32) ? fmaf(cj, wcv, -(sj*wsv))    // P
                            : fmaf(sj, wcv,   cj*wsv);    // Q
    }
    __syncthreads();

    float4* H0a = (float4*)sH0 + lane*8;          // row lane
    float4* H0b = (float4*)sH0 + (lane+64)*8;     // row lane+64
    float4* H1a = (float4*)sH1 + lane*8;
    float4* H1b = (float4*)sH1 + (lane+64)*8;

    float a0x=0.f,a0y=0.f,a0z=0.f,a0w=0.f;
    float a1x=0.f,a1y=0.f,a1z=0.f,a1w=0.f;
    float a2x=0.f,a2y=0.f,a2z=0.f,a2w=0.f;
    float racc = 0.f;

#pragma unroll 1
    for (int pass = 0; pass < 2; ++pass) {
        const float4* rowsA[4];
        const float4* rowsB[4];
#pragma unroll
        for (int m = 0; m < 4; ++m) {
            rowsA[m] = (const float4*)(TROW + (size_t)((pass*4+m)*128 + lane)*56);
            rowsB[m] = rowsA[m] + 14*64;          // row +64
        }

        float zA[4][4], zB[4][4];
        // ---- r feature + z init, 4 tiles ----
#pragma unroll
        for (int m = 0; m < 4; ++m) {
            float rA, rB;
            {
                const float4 pa = rowsA[m][12], pb = rowsA[m][13];
                float s0 = fmaf(pa.y, sJ[48], -(pa.x * sJ[49]));
                float s1 = fmaf(pa.w, sJ[50], -(pa.z * sJ[51]));
                float s2 = fmaf(pb.y, sJ[52], -(pb.x * sJ[53]));
                rA = sqrtf(fmaf(s0, s0, fmaf(s1, s1, s2*s2)));
            }
            {
                const float4 pa = rowsB[m][12], pb = rowsB[m][13];
                float s0 = fmaf(pa.y, sJ[48], -(pa.x * sJ[49]));
                float s1 = fmaf(pa.w, sJ[50], -(pa.z * sJ[51]));
                float s2 = fmaf(pb.y, sJ[52], -(pb.x * sJ[53]));
                rB = sqrtf(fmaf(s0, s0, fmaf(s1, s1, s2*s2)));
            }
            racc += rA + rB;
            const float* w = W20 + c0;            // row 0 weights, uniform
            zA[m][0] = fmaf(rA, w[0], b0x); zA[m][1] = fmaf(rA, w[1], b0y);
            zA[m][2] = fmaf(rA, w[2], b0z); zA[m][3] = fmaf(rA, w[3], b0w);
            zB[m][0] = fmaf(rB, w[0], b0x); zB[m][1] = fmaf(rB, w[1], b0y);
            zB[m][2] = fmaf(rB, w[2], b0z); zB[m][3] = fmaf(rB, w[3], b0w);
        }

        // ---- 48 cos/sin features: P/Q read once, reused across 4 tiles ----
#pragma unroll
        for (int t = 0; t < 12; ++t) {
            const float4 fA0 = rowsA[0][t], fA1 = rowsA[1][t];
            const float4 fA2 = rowsA[2][t], fA3 = rowsA[3][t];
            const float4 fB0 = rowsB[0][t], fB1 = rowsB[1][t];
            const float4 fB2 = rowsB[2][t], fB3 = rowsB[3][t];
#pragma unroll
            for (int sub = 0; sub < 2; ++sub) {
                const int kd = 2*t + sub;
                const float4 P = *(const float4*)(sPQ + kd*64 + c0);       // bcast
                const float4 Q = *(const float4*)(sPQ + kd*64 + 32 + c0);  // bcast
#pragma unroll
                for (int m = 0; m < 4; ++m) {
                    const float4 fA = (m==0)?fA0:(m==1)?fA1:(m==2)?fA2:fA3;
                    const float4 fB = (m==0)?fB0:(m==1)?fB1:(m==2)?fB2:fB3;
                    const float ciA = sub ? fA.z : fA.x, siA = sub ? fA.w : fA.y;
                    const float ciB = sub ? fB.z : fB.x, siB = sub ? fB.w : fB.y;
                    zA[m][0] = fmaf(ciA, P.x, fmaf(siA, Q.x, zA[m][0]));
                    zA[m][1] = fmaf(ciA, P.y, fmaf(siA, Q.y, zA[m][1]));
                    zA[m][2] = fmaf(ciA, P.z, fmaf(siA, Q.z, zA[m][2]));
                    zA[m][3] = fmaf(ciA, P.w, fmaf(siA, Q.w, zA[m][3]));
                    zB[m][0] = fmaf(ciB, P.x, fmaf(siB, Q.x, zB[m][0]));
                    zB[m][1] = fmaf(ciB, P.y, fmaf(siB, Q.y, zB[m][1]));
                    zB[m][2] = fmaf(ciB, P.z, fmaf(siB, Q.z, zB[m][2]));
                    zB[m][3] = fmaf(ciB, P.w, fmaf(siB, Q.w, zB[m][3]));
                }
            }
        }

        // ---- matvec phases, per tile (fully unrolled: constant m) ----
#pragma unroll
        for (int m = 0; m < 4; ++m) {
            float zA0 = zA[m][0], zA1 = zA[m][1], zA2 = zA[m][2], zA3 = zA[m][3];
            float zB0 = zB[m][0], zB1 = zB[m][1], zB2 = zB[m][2], zB3 = zB[m][3];

            // layer 0 tanh; publish; h* holds h0
            float hA0 = ftanh(zA0), hA1 = ftanh(zA1), hA2 = ftanh(zA2), hA3 = ftanh(zA3);
            float hB0 = ftanh(zB0), hB1 = ftanh(zB1), hB2 = ftanh(zB2), hB3 = ftanh(zB3);
            a0x += hA0 + hB0; a0y += hA1 + hB1; a0z += hA2 + hB2; a0w += hA3 + hB3;
            H0a[wid ^ lx] = make_float4(hA0, hA1, hA2, hA3);
            H0b[wid ^ lx] = make_float4(hB0, hB1, hB2, hB3);
            __syncthreads();

            // layer 1
            zA0 = b1x; zA1 = b1y; zA2 = b1z; zA3 = b1w;
            zB0 = b1x; zB1 = b1y; zB2 = b1z; zB3 = b1w;
#pragma unroll
            for (int kc = 0; kc < 8; ++kc) {
                const float4 hA = H0a[kc ^ lx];
                const float4 hB = H0b[kc ^ lx];
                const float* w0 = W21 + (kc*4+0)*32 + c0;
                const float* w1 = W21 + (kc*4+1)*32 + c0;
                const float* w2 = W21 + (kc*4+2)*32 + c0;
                const float* w3 = W21 + (kc*4+3)*32 + c0;
                zA0 = fmaf(hA.x,w0[0], fmaf(hA.y,w1[0], fmaf(hA.z,w2[0], fmaf(hA.w,w3[0], zA0))));
                zA1 = fmaf(hA.x,w0[1], fmaf(hA.y,w1[1], fmaf(hA.z,w2[1], fmaf(hA.w,w3[1], zA1))));
                zA2 = fmaf(hA.x,w0[2], fmaf(hA.y,w1[2], fmaf(hA.z,w2[2], fmaf(hA.w,w3[2], zA2))));
                zA3 = fmaf(hA.x,w0[3], fmaf(hA.y,w1[3], fmaf(hA.z,w2[3], fmaf(hA.w,w3[3], zA3))));
                zB0 = fmaf(hB.x,w0[0], fmaf(hB.y,w1[0], fmaf(hB.z,w2[0], fmaf(hB.w,w3[0], zB0))));
                zB1 = fmaf(hB.x,w0[1], fmaf(hB.y,w1[1], fmaf(hB.z,w2[1], fmaf(hB.w,w3[1], zB1))));
                zB2 = fmaf(hB.x,w0[2], fmaf(hB.y,w1[2], fmaf(hB.z,w2[2], fmaf(hB.w,w3[2], zB2))));
                zB3 = fmaf(hB.x,w0[3], fmaf(hB.y,w1[3], fmaf(hB.z,w2[3], fmaf(hB.w,w3[3], zB3))));
            }
            hA0 = ftanh(zA0) + hA0; hA1 = ftanh(zA1) + hA1;
            hA2 = ftanh(zA2) + hA2; hA3 = ftanh(zA3) + hA3;
            hB0 = ftanh(zB0) + hB0; hB1 = ftanh(zB1) + hB1;
            hB2 = ftanh(zB2) + hB2; hB3 = ftanh(zB3) + hB3;
            a1x += hA0 + hB0; a1y += hA1 + hB1; a1z += hA2 + hB2; a1w += hA3 + hB3;
            H1a[wid ^ lx] = make_float4(hA0, hA1, hA2, hA3);
            H1b[wid ^ lx] = make_float4(hB0, hB1, hB2, hB3);
            __syncthreads();

            // layer 2
            zA0 = b2x; zA1 = b2y; zA2 = b2z; zA3 = b2w;
            zB0 = b2x; zB1 = b2y; zB2 = b2z; zB3 = b2w;
#pragma unroll
            for (int kc = 0; kc < 8; ++kc) {
                const float4 hA = H1a[kc ^ lx];
                const float4 hB = H1b[kc ^ lx];
                const float* w0 = W22 + (kc*4+0)*32 + c0;
                const float* w1 = W22 + (kc*4+1)*32 + c0;
                const float* w2 = W22 + (kc*4+2)*32 + c0;
                const float* w3 = W22 + (kc*4+3)*32 + c0;
                zA0 = fmaf(hA.x,w0[0], fmaf(hA.y,w1[0], fmaf(hA.z,w2[0], fmaf(hA.w,w3[0], zA0))));
                zA1 = fmaf(hA.x,w0[1], fmaf(hA.y,w1[1], fmaf(hA.z,w2[1], fmaf(hA.w,w3[1], zA1))));
                zA2 = fmaf(hA.x,w0[2], fmaf(hA.y,w1[2], fmaf(hA.z,w2[2], fmaf(hA.w,w3[2], zA2))));
                zA3 = fmaf(hA.x,w0[3], fmaf(hA.y,w1[3], fmaf(hA.z,w2[3], fmaf(hA.w,w3[3], zA3))));
                zB0 = fmaf(hB.x,w0[0], fmaf(hB.y,w1[0], fmaf(hB.z,w2[0], fmaf(hB.w,w3[0], zB0))));
                zB1 = fmaf(hB.x,w0[1], fmaf(hB.y,w1[1], fmaf(hB.z,w2[1], fmaf(hB.w,w3[1], zB1))));
                zB2 = fmaf(hB.x,w0[2], fmaf(hB.y,w1[2], fmaf(hB.z,w2[2], fmaf(hB.w,w3[2], zB2))));
                zB3 = fmaf(hB.x,w0[3], fmaf(hB.y,w1[3], fmaf(hB.z,w2[3], fmaf(hB.w,w3[3], zB3))));
            }
            a2x += ftanh(zA0) + hA0 + ftanh(zB0) + hB0;
            a2y += ftanh(zA1) + hA1 + ftanh(zB1) + hB1;
            a2z += ftanh(zA2) + hA2 + ftanh(zB2) + hB2;
            a2w += ftanh(zA3) + hA3 + ftanh(zB3) + hB3;
        }
    }

    // ---- reductions ----
#pragma unroll
    for (int mask = 1; mask < 64; mask <<= 1) {
        a0x += __shfl_xor(a0x, mask, 64); a0y += __shfl_xor(a0y, mask, 64);
        a0z += __shfl_xor(a0z, mask, 64); a0w += __shfl_xor(a0w, mask, 64);
        a1x += __shfl_xor(a1x, mask, 64); a1y += __shfl_xor(a1y, mask, 64);
        a1z += __shfl_xor(a1z, mask, 64); a1w += __shfl_xor(a1w, mask, 64);
        a2x += __shfl_xor(a2x, mask, 64); a2y += __shfl_xor(a2y, mask, 64);
        a2z += __shfl_xor(a2z, mask, 64); a2w += __shfl_xor(a2w, mask, 64);
        racc += __shfl_xor(racc, mask, 64);
    }
    if (lane == 0) {
        *(float4*)(M0 + j*32 + c0) = make_float4(a0x, a0y, a0z, a0w);
        *(float4*)(M1 + j*32 + c0) = make_float4(a1x, a1y, a1z, a1w);
        *(float4*)(M2 + j*32 + c0) = make_float4(a2x, a2y, a2z, a2w);
        if (wid == 0) RACC[j] = racc;
    }
}

// ---------------------------------------------------------------------------
// h1_all: fused h1 path. 64 blocks x 128 threads (co-resident), spin
// grid-sync via device-scope counter; only layer means cross blocks.
// ---------------------------------------------------------------------------
#define FMA8(fv, wptr) do { \
    const float4* w4_ = (const float4*)(wptr); \
    float4 a_ = w4_[0], b_ = w4_[1]; \
    z[0]=fmaf((fv),a_.x,z[0]); z[1]=fmaf((fv),a_.y,z[1]); \
    z[2]=fmaf((fv),a_.z,z[2]); z[3]=fmaf((fv),a_.w,z[3]); \
    z[4]=fmaf((fv),b_.x,z[4]); z[5]=fmaf((fv),b_.y,z[5]); \
    z[6]=fmaf((fv),b_.z,z[6]); z[7]=fmaf((fv),b_.w,z[7]); \
} while (0)

#define HSTR 65

__device__ __forceinline__ void hsum_atomic(float* HS, const float h[8],
                                            int tid, int c0) {
    float hs[8];
#pragma unroll
    for (int u = 0; u < 8; ++u) {
        hs[u] = h[u];
#pragma unroll
        for (int mask = 8; mask < 64; mask <<= 1)
            hs[u] += __shfl_xor(hs[u], mask, 64);
    }
    if (((tid & 63) >> 3) == 0) {
#pragma unroll
        for (int u = 0; u < 8; ++u) atomicAdd(&HS[c0 + u], hs[u]);
    }
}

__device__ __forceinline__ void gsync(int* cnt, int target, int tid) {
    __syncthreads();
    if (tid == 0) {
        __threadfence();
        atomicAdd(cnt, 1);
        while (atomicAdd(cnt, 0) < target) {}
    }
    __syncthreads();
}

__global__ __launch_bounds__(128) void h1_all(
    const float* __restrict__ Tsc,
    const float* __restrict__ W10, const float* __restrict__ b10,
    const float* __restrict__ W11, const float* __restrict__ b11,
    const float* __restrict__ W12, const float* __restrict__ b12,
    const float* __restrict__ W13, const float* __restrict__ b13,
    const float* __restrict__ Wf,  const float* __restrict__ X,
    const float* __restrict__ TROW,
    const float* __restrict__ CSUM, const float* __restrict__ SSUM,
    const float* __restrict__ RACC,
    const float* __restrict__ M0, const float* __restrict__ M1,
    const float* __restrict__ M2,
    float* __restrict__ HSUM, int* __restrict__ CNT,
    float* __restrict__ out)
{
    __shared__ float sH[16*HSTR];
    __shared__ float sG[64];
    const int tid = threadIdx.x;
    const int gid = blockIdx.x*128 + tid;
    const int j = gid >> 3, qq = gid & 7, c0 = qq*8;
    const int lj = tid >> 3;
    const float inv_n = 1.0f/1024.0f;
    float* myrow = sH + lj*HSTR;

    float h[8];
    // ---------------- layer 0 ----------------
    {
        const float t = Tsc[0];
        float z[8];
#pragma unroll
        for (int u = 0; u < 8; ++u) z[u] = b10[c0+u];
        FMA8(t, W10 + 0*64 + c0);
        FMA8(t, W10 + 17*64 + c0);
#pragma unroll
        for (int k = 0; k < 8; ++k) {
            float s, c; sincospif(2.0f*(float)(k+1)*t, &s, &c);
            FMA8(c, W10 + (1+2*k)*64 + c0);
            FMA8(c, W10 + (18+2*k)*64 + c0);
            FMA8(s, W10 + (2+2*k)*64 + c0);
            FMA8(s, W10 + (19+2*k)*64 + c0);
        }
        FMA8(RACC[j]*inv_n, W10 + 34*64 + c0);
        const float4* rj = (const float4*)(TROW + (size_t)j*56);
#pragma unroll
        for (int tt = 0; tt < 12; ++tt) {
            float4 v = rj[tt];
#pragma unroll
            for (int sub = 0; sub < 2; ++sub) {
                const int kd = 2*tt + sub;
                float cj = sub ? v.z : v.x;
                float sj = sub ? v.w : v.y;
                float Cb = CSUM[kd]*inv_n, Sb = SSUM[kd]*inv_n;
                float cm = fmaf(cj, Cb, sj*Sb);
                float sm = fmaf(Sb, cj, -(Cb*sj));
                int k = kd/3, d = kd - k*3;
                FMA8(cm, W10 + (35 + k*6 + d)*64 + c0);
                FMA8(sm, W10 + (38 + k*6 + d)*64 + c0);
            }
        }
#pragma unroll
        for (int u = 0; u < 8; ++u) {
            h[u] = ftanh(z[u]);                 // layer 0: no residual
            myrow[c0+u] = h[u];
        }
        hsum_atomic(HSUM + 0*64, h, tid, c0);
    }
    gsync(CNT, 64, tid);
    if (tid < 64) sG[tid] = __hip_atomic_load(&HSUM[0*64+tid], __ATOMIC_RELAXED,
                                              __HIP_MEMORY_SCOPE_AGENT) * inv_n;
    __syncthreads();

    // ---------------- layers 1 & 2 ----------------
#pragma unroll 1
    for (int L = 1; L <= 2; ++L) {
        const float* W = (L == 1) ? W11 : W12;
        const float* b = (L == 1) ? b11 : b12;
        const float* M = (L == 1) ? M0  : M1;
        float z[8];
#pragma unroll
        for (int u = 0; u < 8; ++u) z[u] = b[c0+u];
#pragma unroll 4
        for (int p = 0; p < 64; ++p) FMA8(myrow[p], W + p*64 + c0);
#pragma unroll 4
        for (int p = 0; p < 64; ++p) FMA8(sG[p], W + (64+p)*64 + c0);
        const float* mrow = M + j*32;
#pragma unroll 4
        for (int p = 0; p < 32; ++p) FMA8(mrow[p]*inv_n, W + (128+p)*64 + c0);
#pragma unroll
        for (int u = 0; u < 8; ++u) h[u] = ftanh(z[u]) + myrow[c0+u];  // residual
        __syncthreads();                       // all reads of sH done
#pragma unroll
        for (int u = 0; u < 8; ++u) myrow[c0+u] = h[u];
        hsum_atomic(HSUM + L*64, h, tid, c0);
        gsync(CNT, 64*(L+1), tid);
        if (tid < 64) sG[tid] = __hip_atomic_load(&HSUM[L*64+tid], __ATOMIC_RELAXED,
                                                  __HIP_MEMORY_SCOPE_AGENT) * inv_n;
        __syncthreads();
    }

    // ---------------- layer 3 + output ----------------
    {
        float z[8];
#pragma unroll
        for (int u = 0; u < 8; ++u) z[u] = b13[c0+u];
#pragma unroll 4
        for (int p = 0; p < 64; ++p) FMA8(myrow[p], W13 + p*64 + c0);
#pragma unroll 4
        for (int p = 0; p < 64; ++p) FMA8(sG[p], W13 + (64+p)*64 + c0);
        const float* mrow = M2 + j*32;
#pragma unroll 4
        for (int p = 0; p < 32; ++p) FMA8(mrow[p]*inv_n, W13 + (128+p)*64 + c0);
#pragma unroll
        for (int u = 0; u < 8; ++u) h[u] = ftanh(z[u]) + myrow[c0+u];

        float p0 = 0.f, p1 = 0.f, p2 = 0.f;
#pragma unroll
        for (int u = 0; u < 8; ++u) {
            const float* wf = Wf + (c0+u)*3;
            p0 = fmaf(h[u], wf[0], p0);
            p1 = fmaf(h[u], wf[1], p1);
            p2 = fmaf(h[u], wf[2], p2);
        }
#pragma unroll
        for (int m = 1; m < 8; m <<= 1) {
            p0 += __shfl_xor(p0, m, 64);
            p1 += __shfl_xor(p1, m, 64);
            p2 += __shfl_xor(p2, m, 64);
        }
        if (qq == 0) {
#pragma unroll
            for (int d = 0; d < 3; ++d) {
                float fx = 2.0f * X[j*3 + d];
                fx = fminf(fmaxf(fx, -10.0f), 10.0f);
                float s = (d == 0 ? p0 : (d == 1 ? p1 : p2));
                out[j*3 + d] = -s * fx;
            }
        }
    }
}

// ---------------------------------------------------------------------------
extern "C" void kernel_launch(void* const* d_in, const int* in_sizes, int n_in,
                              void* d_out, int out_size, void* d_ws, size_t ws_size,
                              hipStream_t stream)
{
    const float* X   = (const float*)d_in[0];
    const float* Tsc = (const float*)d_in[1];
    const float* W10 = (const float*)d_in[2];  const float* b10 = (const float*)d_in[3];
    const float* W11 = (const float*)d_in[4];  const float* b11 = (const float*)d_in[5];
    const float* W12 = (const float*)d_in[6];  const float* b12 = (const float*)d_in[7];
    const float* W13 = (const float*)d_in[8];  const float* b13 = (const float*)d_in[9];
    const float* W20 = (const float*)d_in[10]; const float* b20 = (const float*)d_in[11];
    const float* W21 = (const float*)d_in[12]; const float* b21 = (const float*)d_in[13];
    const float* W22 = (const float*)d_in[14]; const float* b22 = (const float*)d_in[15];
    const float* Wf  = (const float*)d_in[16];

    float* ws  = (float*)d_ws;
    float* out = (float*)d_out;

    float* TROW = ws + OF_TROW;
    float* CSUM = ws + OF_CSUM; float* SSUM = ws + OF_SSUM;
    float* HSUM = ws + OF_HSUM; int*   CNT  = (int*)(ws + OF_CNT);
    float* RACC = ws + OF_RACC;
    float* M0 = ws + OF_M0; float* M1 = ws + OF_M1; float* M2 = ws + OF_M2;

    k1_tables<<<1, 1024, 0, stream>>>(X, TROW, CSUM, SSUM, HSUM, CNT);
    k2_pairs<<<NP, 512, 0, stream>>>(W20, b20, W21, b21, W22, b22,
                                     TROW, RACC, M0, M1, M2);
    h1_all<<<64, 128, 0, stream>>>(Tsc, W10, b10, W11, b11, W12, b12, W13, b13,
                                   Wf, X, TROW, CSUM, SSUM, RACC,
                                   M0, M1, M2, HSUM, CNT, out);
}

// Round 14
// 414.090 us; speedup vs baseline: 1.8727x; 1.8727x over previous
//
#include <hip/hip_runtime.h>
#include <math.h>

// FermiNet-like forward, N=1024, DIM=3, all fp32.
//
// v14 = exact revert to v12/v10 (stable best: 415us total; k2 229us).
// v13's 4-tile batching hit the register-tier trap: at (512,4) the
// allocator targets the 64-reg/8-waves-EU tier regardless of live pressure
// (~110 live -> ~50 regs spilled -> 241/404 MB scratch, k2 578us).
//
// Final structure map (rounds 1-13):
//  * k2: block=column j, 512 thr = 8 waves; lane=row pair {lane,lane+64};
//    wave owns 4 channels; 8 tiles x 128 rows. Wave-uniform scalar weight
//    loads (SGPR path), P/Q trig-fold per block (LDS bcast), XOR-swizzled
//    sH exchange, 56 VGPR (live ~55 fits the 64-tier), zero spill,
//    VALUBusy ~82%, co-bound VALU+DS.
//  * Refuted improvement axes: packed f32 math (v11: pack/unpack overhead),
//    tile batching (v13: register-tier trap), more rows/lane (v5/v8: same),
//    launch restructuring of the ~185us tail (v5/v10/v11: invariant).
//  * h1_all: 64x128 persistent, spin grid-sync, layer means via atomics.

#define NP 1024

// ---- workspace offsets (in floats) ----
static const size_t OF_TROW = 0;                    // NP*56 row-major trig
static const size_t OF_CSUM = OF_TROW + NP*56;      // 24  sum_i cos
static const size_t OF_SSUM = OF_CSUM + 24;         // 24  sum_i sin
static const size_t OF_HSUM = OF_SSUM + 24;         // 3*64  h1 row-sum per layer
static const size_t OF_CNT  = OF_HSUM + 192;        // 4 (int counter in [0])
static const size_t OF_RACC = OF_CNT + 4;           // 1024  sum_i r(i,j)
static const size_t OF_M0   = OF_RACC + NP;         // 1024*32 sum_i h2 stage0
static const size_t OF_M1   = OF_M0 + NP*32;        // 1024*32 stage1
static const size_t OF_M2   = OF_M1 + NP*32;        // 1024*32 stage2
// end: OF_M2 + NP*32 = 156388 floats (~626 KB)

__device__ __forceinline__ float ftanh(float x) {
    float e = __expf(2.0f * x);
    return 1.0f - __fdividef(2.0f, e + 1.0f);
}

// ---------------------------------------------------------------------------
// K1: per-particle trig rows (TROW[i][56]) + column sums + zero HSUM/CNT.
// ---------------------------------------------------------------------------
__global__ __launch_bounds__(1024) void k1_tables(
    const float* __restrict__ X,
    float* __restrict__ TROW,
    float* __restrict__ CSUM, float* __restrict__ SSUM,
    float* __restrict__ HSUM, int* __restrict__ CNT)
{
    const int i = threadIdx.x;
    float ck[24], sk[24], cp[3], sp[3];
#pragma unroll
    for (int d = 0; d < 3; ++d) {
        float x = X[i*3 + d];
        sincospif(x, &sp[d], &cp[d]);
#pragma unroll
        for (int k = 0; k < 8; ++k) {
            float s, c;
            sincospif(2.0f*(float)(k+1)*x, &s, &c);
            ck[k*3 + d] = c;  sk[k*3 + d] = s;
        }
    }
    float4* row = (float4*)(TROW + (size_t)i*56);
#pragma unroll
    for (int t = 0; t < 12; ++t)
        row[t] = make_float4(ck[2*t], sk[2*t], ck[2*t+1], sk[2*t+1]);
    row[12] = make_float4(cp[0], sp[0], cp[1], sp[1]);
    row[13] = make_float4(cp[2], sp[2], 0.f, 0.f);

    __shared__ float part[48*16];
    const int lane = i & 63, wv = i >> 6;
#pragma unroll
    for (int v = 0; v < 24; ++v) {
        float a = ck[v], b = sk[v];
#pragma unroll
        for (int off = 32; off; off >>= 1) {
            a += __shfl_down(a, off, 64);
            b += __shfl_down(b, off, 64);
        }
        if (lane == 0) { part[v*16 + wv] = a; part[(24+v)*16 + wv] = b; }
    }
    __syncthreads();
    if (i < 48) {
        float s = 0.f;
#pragma unroll
        for (int w = 0; w < 16; ++w) s += part[i*16 + w];
        if (i < 24) CSUM[i] = s; else SSUM[i-24] = s;
    }
    if (i < 192) HSUM[i] = 0.0f;
    if (i == 200) CNT[0] = 0;
}

// ---------------------------------------------------------------------------
// K2: pair kernel. Block = column j, 512 threads = 8 waves.
// P/Q folded per block; inner loop = ci*P + si*Q (scalar fp32, v10 form).
// ---------------------------------------------------------------------------
__global__ __launch_bounds__(512, 4) void k2_pairs(
    const float* __restrict__ W20, const float* __restrict__ b20,
    const float* __restrict__ W21, const float* __restrict__ b21,
    const float* __restrict__ W22, const float* __restrict__ b22,
    const float* __restrict__ TROW,
    float* __restrict__ RACC, float* __restrict__ M0,
    float* __restrict__ M1, float* __restrict__ M2)
{
    __shared__ __align__(16) float sH0[128*32];   // 16 KB, XOR-swizzled slots
    __shared__ __align__(16) float sH1[128*32];   // 16 KB
    __shared__ __align__(16) float sJ[56];        // row j of TROW
    __shared__ __align__(16) float sPQ[24*64];    // [kd][0:32]=P, [32:64]=Q

    const int tid  = threadIdx.x;
    const int lane = tid & 63;
    const int wid  = __builtin_amdgcn_readfirstlane(tid >> 6);   // 0..7 uniform
    const int c0   = wid * 4;                                    // uniform
    const int j    = blockIdx.x;
    const int lx   = lane & 7;

    if (tid < 14) ((float4*)sJ)[tid] = ((const float4*)(TROW + (size_t)j*56))[tid];

    // biases: wave-uniform -> SGPRs
    const float b0x = b20[c0+0], b0y = b20[c0+1], b0z = b20[c0+2], b0w = b20[c0+3];
    const float b1x = b21[c0+0], b1y = b21[c0+1], b1z = b21[c0+2], b1w = b21[c0+3];
    const float b2x = b22[c0+0], b2y = b22[c0+1], b2z = b22[c0+2], b2w = b22[c0+3];
    __syncthreads();

    // ---- fold P/Q for this column j (once per block) ----
    for (int idx = tid; idx < 24*64; idx += 512) {
        const int kd = idx >> 6;
        const int e  = idx & 63;
        const int c  = e & 31;
        const int k = kd/3, d = kd - k*3;
        const float wcv = W20[(1 + k*6 + d)*32 + c];
        const float wsv = W20[(4 + k*6 + d)*32 + c];
        const float cj = sJ[2*kd], sj = sJ[2*kd+1];
        sPQ[idx] = (e < 32) ? fmaf(cj, wcv, -(sj*wsv))    // P
                            : fmaf(sj, wcv,   cj*wsv);    // Q
    }
    __syncthreads();

    float4* H0a = (float4*)sH0 + lane*8;          // row lane
    float4* H0b = (float4*)sH0 + (lane+64)*8;     // row lane+64
    float4* H1a = (float4*)sH1 + lane*8;
    float4* H1b = (float4*)sH1 + (lane+64)*8;

    float a0x=0.f,a0y=0.f,a0z=0.f,a0w=0.f;
    float a1x=0.f,a1y=0.f,a1z=0.f,a1w=0.f;
    float a2x=0.f,a2y=0.f,a2z=0.f,a2w=0.f;
    float racc = 0.f;

#pragma unroll 1
    for (int tile = 0; tile < 8; ++tile) {
        const float4* rowA = (const float4*)(TROW + (size_t)(tile*128 + lane)*56);
        const float4* rowB = rowA + 14*64;        // row +64 (56 floats * 64)

        // ---- r feature, both rows ----
        float rA, rB;
        {
            const float4 pa = rowA[12], pb = rowA[13];
            float s0 = fmaf(pa.y, sJ[48], -(pa.x * sJ[49]));
            float s1 = fmaf(pa.w, sJ[50], -(pa.z * sJ[51]));
            float s2 = fmaf(pb.y, sJ[52], -(pb.x * sJ[53]));
            rA = sqrtf(fmaf(s0, s0, fmaf(s1, s1, s2*s2)));
        }
        {
            const float4 pa = rowB[12], pb = rowB[13];
            float s0 = fmaf(pa.y, sJ[48], -(pa.x * sJ[49]));
            float s1 = fmaf(pa.w, sJ[50], -(pa.z * sJ[51]));
            float s2 = fmaf(pb.y, sJ[52], -(pb.x * sJ[53]));
            rB = sqrtf(fmaf(s0, s0, fmaf(s1, s1, s2*s2)));
        }
        racc += rA + rB;

        float zA0, zA1, zA2, zA3, zB0, zB1, zB2, zB3;
        {
            const float* w = W20 + c0;            // row 0 weights, uniform
            zA0 = fmaf(rA, w[0], b0x); zA1 = fmaf(rA, w[1], b0y);
            zA2 = fmaf(rA, w[2], b0z); zA3 = fmaf(rA, w[3], b0w);
            zB0 = fmaf(rB, w[0], b0x); zB1 = fmaf(rB, w[1], b0y);
            zB2 = fmaf(rB, w[2], b0z); zB3 = fmaf(rB, w[3], b0w);
        }
        // ---- 48 cos/sin features via folded P/Q ----
#pragma unroll
        for (int t = 0; t < 12; ++t) {
            const float4 fA = rowA[t], fB = rowB[t];
#pragma unroll
            for (int sub = 0; sub < 2; ++sub) {
                const int kd = 2*t + sub;
                const float4 P = *(const float4*)(sPQ + kd*64 + c0);       // bcast
                const float4 Q = *(const float4*)(sPQ + kd*64 + 32 + c0);  // bcast
                const float ciA = sub ? fA.z : fA.x, siA = sub ? fA.w : fA.y;
                const float ciB = sub ? fB.z : fB.x, siB = sub ? fB.w : fB.y;
                zA0 = fmaf(ciA, P.x, fmaf(siA, Q.x, zA0));
                zA1 = fmaf(ciA, P.y, fmaf(siA, Q.y, zA1));
                zA2 = fmaf(ciA, P.z, fmaf(siA, Q.z, zA2));
                zA3 = fmaf(ciA, P.w, fmaf(siA, Q.w, zA3));
                zB0 = fmaf(ciB, P.x, fmaf(siB, Q.x, zB0));
                zB1 = fmaf(ciB, P.y, fmaf(siB, Q.y, zB1));
                zB2 = fmaf(ciB, P.z, fmaf(siB, Q.z, zB2));
                zB3 = fmaf(ciB, P.w, fmaf(siB, Q.w, zB3));
            }
        }

        // ---- layer 0 tanh; publish; h* holds h0 ----
        float hA0 = ftanh(zA0), hA1 = ftanh(zA1), hA2 = ftanh(zA2), hA3 = ftanh(zA3);
        float hB0 = ftanh(zB0), hB1 = ftanh(zB1), hB2 = ftanh(zB2), hB3 = ftanh(zB3);
        a0x += hA0 + hB0; a0y += hA1 + hB1; a0z += hA2 + hB2; a0w += hA3 + hB3;
        H0a[wid ^ lx] = make_float4(hA0, hA1, hA2, hA3);
        H0b[wid ^ lx] = make_float4(hB0, hB1, hB2, hB3);
        __syncthreads();

        // ---- layer 1 ----
        zA0 = b1x; zA1 = b1y; zA2 = b1z; zA3 = b1w;
        zB0 = b1x; zB1 = b1y; zB2 = b1z; zB3 = b1w;
#pragma unroll
        for (int kc = 0; kc < 8; ++kc) {
            const float4 hA = H0a[kc ^ lx];
            const float4 hB = H0b[kc ^ lx];
            const float* w0 = W21 + (kc*4+0)*32 + c0;
            const float* w1 = W21 + (kc*4+1)*32 + c0;
            const float* w2 = W21 + (kc*4+2)*32 + c0;
            const float* w3 = W21 + (kc*4+3)*32 + c0;
            zA0 = fmaf(hA.x,w0[0], fmaf(hA.y,w1[0], fmaf(hA.z,w2[0], fmaf(hA.w,w3[0], zA0))));
            zA1 = fmaf(hA.x,w0[1], fmaf(hA.y,w1[1], fmaf(hA.z,w2[1], fmaf(hA.w,w3[1], zA1))));
            zA2 = fmaf(hA.x,w0[2], fmaf(hA.y,w1[2], fmaf(hA.z,w2[2], fmaf(hA.w,w3[2], zA2))));
            zA3 = fmaf(hA.x,w0[3], fmaf(hA.y,w1[3], fmaf(hA.z,w2[3], fmaf(hA.w,w3[3], zA3))));
            zB0 = fmaf(hB.x,w0[0], fmaf(hB.y,w1[0], fmaf(hB.z,w2[0], fmaf(hB.w,w3[0], zB0))));
            zB1 = fmaf(hB.x,w0[1], fmaf(hB.y,w1[1], fmaf(hB.z,w2[1], fmaf(hB.w,w3[1], zB1))));
            zB2 = fmaf(hB.x,w0[2], fmaf(hB.y,w1[2], fmaf(hB.z,w2[2], fmaf(hB.w,w3[2], zB2))));
            zB3 = fmaf(hB.x,w0[3], fmaf(hB.y,w1[3], fmaf(hB.z,w2[3], fmaf(hB.w,w3[3], zB3))));
        }
        hA0 = ftanh(zA0) + hA0; hA1 = ftanh(zA1) + hA1;
        hA2 = ftanh(zA2) + hA2; hA3 = ftanh(zA3) + hA3;
        hB0 = ftanh(zB0) + hB0; hB1 = ftanh(zB1) + hB1;
        hB2 = ftanh(zB2) + hB2; hB3 = ftanh(zB3) + hB3;
        a1x += hA0 + hB0; a1y += hA1 + hB1; a1z += hA2 + hB2; a1w += hA3 + hB3;
        H1a[wid ^ lx] = make_float4(hA0, hA1, hA2, hA3);
        H1b[wid ^ lx] = make_float4(hB0, hB1, hB2, hB3);
        __syncthreads();

        // ---- layer 2 ----
        zA0 = b2x; zA1 = b2y; zA2 = b2z; zA3 = b2w;
        zB0 = b2x; zB1 = b2y; zB2 = b2z; zB3 = b2w;
#pragma unroll
        for (int kc = 0; kc < 8; ++kc) {
            const float4 hA = H1a[kc ^ lx];
            const float4 hB = H1b[kc ^ lx];
            const float* w0 = W22 + (kc*4+0)*32 + c0;
            const float* w1 = W22 + (kc*4+1)*32 + c0;
            const float* w2 = W22 + (kc*4+2)*32 + c0;
            const float* w3 = W22 + (kc*4+3)*32 + c0;
            zA0 = fmaf(hA.x,w0[0], fmaf(hA.y,w1[0], fmaf(hA.z,w2[0], fmaf(hA.w,w3[0], zA0))));
            zA1 = fmaf(hA.x,w0[1], fmaf(hA.y,w1[1], fmaf(hA.z,w2[1], fmaf(hA.w,w3[1], zA1))));
            zA2 = fmaf(hA.x,w0[2], fmaf(hA.y,w1[2], fmaf(hA.z,w2[2], fmaf(hA.w,w3[2], zA2))));
            zA3 = fmaf(hA.x,w0[3], fmaf(hA.y,w1[3], fmaf(hA.z,w2[3], fmaf(hA.w,w3[3], zA3))));
            zB0 = fmaf(hB.x,w0[0], fmaf(hB.y,w1[0], fmaf(hB.z,w2[0], fmaf(hB.w,w3[0], zB0))));
            zB1 = fmaf(hB.x,w0[1], fmaf(hB.y,w1[1], fmaf(hB.z,w2[1], fmaf(hB.w,w3[1], zB1))));
            zB2 = fmaf(hB.x,w0[2], fmaf(hB.y,w1[2], fmaf(hB.z,w2[2], fmaf(hB.w,w3[2], zB2))));
            zB3 = fmaf(hB.x,w0[3], fmaf(hB.y,w1[3], fmaf(hB.z,w2[3], fmaf(hB.w,w3[3], zB3))));
        }
        a2x += ftanh(zA0) + hA0 + ftanh(zB0) + hB0;
        a2y += ftanh(zA1) + hA1 + ftanh(zB1) + hB1;
        a2z += ftanh(zA2) + hA2 + ftanh(zB2) + hB2;
        a2w += ftanh(zA3) + hA3 + ftanh(zB3) + hB3;
    }

    // ---- reductions ----
#pragma unroll
    for (int mask = 1; mask < 64; mask <<= 1) {
        a0x += __shfl_xor(a0x, mask, 64); a0y += __shfl_xor(a0y, mask, 64);
        a0z += __shfl_xor(a0z, mask, 64); a0w += __shfl_xor(a0w, mask, 64);
        a1x += __shfl_xor(a1x, mask, 64); a1y += __shfl_xor(a1y, mask, 64);
        a1z += __shfl_xor(a1z, mask, 64); a1w += __shfl_xor(a1w, mask, 64);
        a2x += __shfl_xor(a2x, mask, 64); a2y += __shfl_xor(a2y, mask, 64);
        a2z += __shfl_xor(a2z, mask, 64); a2w += __shfl_xor(a2w, mask, 64);
        racc += __shfl_xor(racc, mask, 64);
    }
    if (lane == 0) {
        *(float4*)(M0 + j*32 + c0) = make_float4(a0x, a0y, a0z, a0w);
        *(float4*)(M1 + j*32 + c0) = make_float4(a1x, a1y, a1z, a1w);
        *(float4*)(M2 + j*32 + c0) = make_float4(a2x, a2y, a2z, a2w);
        if (wid == 0) RACC[j] = racc;
    }
}

// ---------------------------------------------------------------------------
// h1_all: fused h1 path. 64 blocks x 128 threads (co-resident), spin
// grid-sync via device-scope counter; only layer means cross blocks.
// thread <-> (row j, 8-channel chunk qq); h-rows live in LDS sH[16][65].
// ---------------------------------------------------------------------------
#define FMA8(fv, wptr) do { \
    const float4* w4_ = (const float4*)(wptr); \
    float4 a_ = w4_[0], b_ = w4_[1]; \
    z[0]=fmaf((fv),a_.x,z[0]); z[1]=fmaf((fv),a_.y,z[1]); \
    z[2]=fmaf((fv),a_.z,z[2]); z[3]=fmaf((fv),a_.w,z[3]); \
    z[4]=fmaf((fv),b_.x,z[4]); z[5]=fmaf((fv),b_.y,z[5]); \
    z[6]=fmaf((fv),b_.z,z[6]); z[7]=fmaf((fv),b_.w,z[7]); \
} while (0)

#define HSTR 65

__device__ __forceinline__ void hsum_atomic(float* HS, const float h[8],
                                            int tid, int c0) {
    float hs[8];
#pragma unroll
    for (int u = 0; u < 8; ++u) {
        hs[u] = h[u];
#pragma unroll
        for (int mask = 8; mask < 64; mask <<= 1)
            hs[u] += __shfl_xor(hs[u], mask, 64);
    }
    if (((tid & 63) >> 3) == 0) {
#pragma unroll
        for (int u = 0; u < 8; ++u) atomicAdd(&HS[c0 + u], hs[u]);
    }
}

__device__ __forceinline__ void gsync(int* cnt, int target, int tid) {
    __syncthreads();
    if (tid == 0) {
        __threadfence();
        atomicAdd(cnt, 1);
        while (atomicAdd(cnt, 0) < target) {}
    }
    __syncthreads();
}

__global__ __launch_bounds__(128) void h1_all(
    const float* __restrict__ Tsc,
    const float* __restrict__ W10, const float* __restrict__ b10,
    const float* __restrict__ W11, const float* __restrict__ b11,
    const float* __restrict__ W12, const float* __restrict__ b12,
    const float* __restrict__ W13, const float* __restrict__ b13,
    const float* __restrict__ Wf,  const float* __restrict__ X,
    const float* __restrict__ TROW,
    const float* __restrict__ CSUM, const float* __restrict__ SSUM,
    const float* __restrict__ RACC,
    const float* __restrict__ M0, const float* __restrict__ M1,
    const float* __restrict__ M2,
    float* __restrict__ HSUM, int* __restrict__ CNT,
    float* __restrict__ out)
{
    __shared__ float sH[16*HSTR];
    __shared__ float sG[64];
    const int tid = threadIdx.x;
    const int gid = blockIdx.x*128 + tid;
    const int j = gid >> 3, qq = gid & 7, c0 = qq*8;
    const int lj = tid >> 3;
    const float inv_n = 1.0f/1024.0f;
    float* myrow = sH + lj*HSTR;

    float h[8];
    // ---------------- layer 0 ----------------
    {
        const float t = Tsc[0];
        float z[8];
#pragma unroll
        for (int u = 0; u < 8; ++u) z[u] = b10[c0+u];
        FMA8(t, W10 + 0*64 + c0);
        FMA8(t, W10 + 17*64 + c0);
#pragma unroll
        for (int k = 0; k < 8; ++k) {
            float s, c; sincospif(2.0f*(float)(k+1)*t, &s, &c);
            FMA8(c, W10 + (1+2*k)*64 + c0);
            FMA8(c, W10 + (18+2*k)*64 + c0);
            FMA8(s, W10 + (2+2*k)*64 + c0);
            FMA8(s, W10 + (19+2*k)*64 + c0);
        }
        FMA8(RACC[j]*inv_n, W10 + 34*64 + c0);
        const float4* rj = (const float4*)(TROW + (size_t)j*56);
#pragma unroll
        for (int tt = 0; tt < 12; ++tt) {
            float4 v = rj[tt];
#pragma unroll
            for (int sub = 0; sub < 2; ++sub) {
                const int kd = 2*tt + sub;
                float cj = sub ? v.z : v.x;
                float sj = sub ? v.w : v.y;
                float Cb = CSUM[kd]*inv_n, Sb = SSUM[kd]*inv_n;
                float cm = fmaf(cj, Cb, sj*Sb);
                float sm = fmaf(Sb, cj, -(Cb*sj));
                int k = kd/3, d = kd - k*3;
                FMA8(cm, W10 + (35 + k*6 + d)*64 + c0);
                FMA8(sm, W10 + (38 + k*6 + d)*64 + c0);
            }
        }
#pragma unroll
        for (int u = 0; u < 8; ++u) {
            h[u] = ftanh(z[u]);                 // layer 0: no residual
            myrow[c0+u] = h[u];
        }
        hsum_atomic(HSUM + 0*64, h, tid, c0);
    }
    gsync(CNT, 64, tid);
    if (tid < 64) sG[tid] = __hip_atomic_load(&HSUM[0*64+tid], __ATOMIC_RELAXED,
                                              __HIP_MEMORY_SCOPE_AGENT) * inv_n;
    __syncthreads();

    // ---------------- layers 1 & 2 ----------------
#pragma unroll 1
    for (int L = 1; L <= 2; ++L) {
        const float* W = (L == 1) ? W11 : W12;
        const float* b = (L == 1) ? b11 : b12;
        const float* M = (L == 1) ? M0  : M1;
        float z[8];
#pragma unroll
        for (int u = 0; u < 8; ++u) z[u] = b[c0+u];
#pragma unroll 4
        for (int p = 0; p < 64; ++p) FMA8(myrow[p], W + p*64 + c0);
#pragma unroll 4
        for (int p = 0; p < 64; ++p) FMA8(sG[p], W + (64+p)*64 + c0);
        const float* mrow = M + j*32;
#pragma unroll 4
        for (int p = 0; p < 32; ++p) FMA8(mrow[p]*inv_n, W + (128+p)*64 + c0);
#pragma unroll
        for (int u = 0; u < 8; ++u) h[u] = ftanh(z[u]) + myrow[c0+u];  // residual
        __syncthreads();                       // all reads of sH done
#pragma unroll
        for (int u = 0; u < 8; ++u) myrow[c0+u] = h[u];
        hsum_atomic(HSUM + L*64, h, tid, c0);
        gsync(CNT, 64*(L+1), tid);
        if (tid < 64) sG[tid] = __hip_atomic_load(&HSUM[L*64+tid], __ATOMIC_RELAXED,
                                                  __HIP_MEMORY_SCOPE_AGENT) * inv_n;
        __syncthreads();
    }

    // ---------------- layer 3 + output ----------------
    {
        float z[8];
#pragma unroll
        for (int u = 0; u < 8; ++u) z[u] = b13[c0+u];
#pragma unroll 4
        for (int p = 0; p < 64; ++p) FMA8(myrow[p], W13 + p*64 + c0);
#pragma unroll 4
        for (int p = 0; p < 64; ++p) FMA8(sG[p], W13 + (64+p)*64 + c0);
        const float* mrow = M2 + j*32;
#pragma unroll 4
        for (int p = 0; p < 32; ++p) FMA8(mrow[p]*inv_n, W13 + (128+p)*64 + c0);
#pragma unroll
        for (int u = 0; u < 8; ++u) h[u] = ftanh(z[u]) + myrow[c0+u];

        float p0 = 0.f, p1 = 0.f, p2 = 0.f;
#pragma unroll
        for (int u = 0; u < 8; ++u) {
            const float* wf = Wf + (c0+u)*3;
            p0 = fmaf(h[u], wf[0], p0);
            p1 = fmaf(h[u], wf[1], p1);
            p2 = fmaf(h[u], wf[2], p2);
        }
#pragma unroll
        for (int m = 1; m < 8; m <<= 1) {
            p0 += __shfl_xor(p0, m, 64);
            p1 += __shfl_xor(p1, m, 64);
            p2 += __shfl_xor(p2, m, 64);
        }
        if (qq == 0) {
#pragma unroll
            for (int d = 0; d < 3; ++d) {
                float fx = 2.0f * X[j*3 + d];
                fx = fminf(fmaxf(fx, -10.0f), 10.0f);
                float s = (d == 0 ? p0 : (d == 1 ? p1 : p2));
                out[j*3 + d] = -s * fx;
            }
        }
    }
}

// ---------------------------------------------------------------------------
extern "C" void kernel_launch(void* const* d_in, const int* in_sizes, int n_in,
                              void* d_out, int out_size, void* d_ws, size_t ws_size,
                              hipStream_t stream)
{
    const float* X   = (const float*)d_in[0];
    const float* Tsc = (const float*)d_in[1];
    const float* W10 = (const float*)d_in[2];  const float* b10 = (const float*)d_in[3];
    const float* W11 = (const float*)d_in[4];  const float* b11 = (const float*)d_in[5];
    const float* W12 = (const float*)d_in[6];  const float* b12 = (const float*)d_in[7];
    const float* W13 = (const float*)d_in[8];  const float* b13 = (const float*)d_in[9];
    const float* W20 = (const float*)d_in[10]; const float* b20 = (const float*)d_in[11];
    const float* W21 = (const float*)d_in[12]; const float* b21 = (const float*)d_in[13];
    const float* W22 = (const float*)d_in[14]; const float* b22 = (const float*)d_in[15];
    const float* Wf  = (const float*)d_in[16];

    float* ws  = (float*)d_ws;
    float* out = (float*)d_out;

    float* TROW = ws + OF_TROW;
    float* CSUM = ws + OF_CSUM; float* SSUM = ws + OF_SSUM;
    float* HSUM = ws + OF_HSUM; int*   CNT  = (int*)(ws + OF_CNT);
    float* RACC = ws + OF_RACC;
    float* M0 = ws + OF_M0; float* M1 = ws + OF_M1; float* M2 = ws + OF_M2;

    k1_tables<<<1, 1024, 0, stream>>>(X, TROW, CSUM, SSUM, HSUM, CNT);
    k2_pairs<<<NP, 512, 0, stream>>>(W20, b20, W21, b21, W22, b22,
                                     TROW, RACC, M0, M1, M2);
    h1_all<<<64, 128, 0, stream>>>(Tsc, W10, b10, W11, b11, W12, b12, W13, b13,
                                   Wf, X, TROW, CSUM, SSUM, RACC,
                                   M0, M1, M2, HSUM, CNT, out);
}